// Round 5
// baseline (2151.134 us; speedup 1.0000x reference)
//
#include <hip/hip_runtime.h>

typedef unsigned long long u64;
typedef unsigned int u32;

#define V_ 1000000
#define STEPS_ 10
#define EPS_ 1e-5f
#define MARGIN_ 0.06f
#define FP8_SCALE 2048.0f
#define FP8_INV (1.0f / 2048.0f)
#define NCH 8192        // chunks covering V
#define CH 123          // rows per chunk
#define GRID_ 1024      // 4 blocks/CU x 256 CUs -> guaranteed co-resident
#define NSTEP_BLK 64    // blocks doing the transformer
#define BAIL_ (1u << 21)

// ---------------------------------------------------------------------------
// Packed (value, ~idx) so u64 max == argmax with lowest-index tie-break.
// ---------------------------------------------------------------------------
__device__ __forceinline__ u64 pack_best(float v, int idx) {
    u32 u = __float_as_uint(v);
    u = (u & 0x80000000u) ? ~u : (u | 0x80000000u);
    return ((u64)u << 32) | (u64)(~(u32)idx);
}
__device__ __forceinline__ int unpack_idx(u64 p) { return (int)(~(u32)p); }
__device__ __forceinline__ float unpack_val(u64 p) {
    u32 hi = (u32)(p >> 32);
    return __uint_as_float((hi & 0x80000000u) ? (hi ^ 0x80000000u) : ~hi);
}
__device__ __forceinline__ u64 shfl_xor_u64(u64 v, int m) {
    u32 lo = (u32)v, hi = (u32)(v >> 32);
    lo = (u32)__shfl_xor((int)lo, m);
    hi = (u32)__shfl_xor((int)hi, m);
    return ((u64)hi << 32) | lo;
}

// fp8(e4m3, OCP, HW cvt) 16-element dot: u = 16 packed fp8, q[16] pre-scaled.
#define FP8_DOT16(u, q, p) do { \
    auto a0 = __builtin_amdgcn_cvt_pk_f32_fp8((u).x, false); \
    auto a1 = __builtin_amdgcn_cvt_pk_f32_fp8((u).x, true);  \
    auto b0 = __builtin_amdgcn_cvt_pk_f32_fp8((u).y, false); \
    auto b1 = __builtin_amdgcn_cvt_pk_f32_fp8((u).y, true);  \
    auto c0 = __builtin_amdgcn_cvt_pk_f32_fp8((u).z, false); \
    auto c1 = __builtin_amdgcn_cvt_pk_f32_fp8((u).z, true);  \
    auto d0 = __builtin_amdgcn_cvt_pk_f32_fp8((u).w, false); \
    auto d1 = __builtin_amdgcn_cvt_pk_f32_fp8((u).w, true);  \
    p = q[0]*a0[0] + q[1]*a0[1] + q[2]*a1[0] + q[3]*a1[1] \
      + q[4]*b0[0] + q[5]*b0[1] + q[6]*b1[0] + q[7]*b1[1] \
      + q[8]*c0[0] + q[9]*c0[1] + q[10]*c1[0] + q[11]*c1[1] \
      + q[12]*d0[0] + q[13]*d0[1] + q[14]*d1[0] + q[15]*d1[1]; \
} while (0)

// ---------------------------------------------------------------------------
// Barriers. All counters are single-use slots zeroed by one memset per launch.
// sub_bar: flat counter among NSTEP_BLK blocks.
// tree_bar: 64 padded leaf counters (16 blocks each) -> root; all 1024 blocks.
// Release on the arrive-RMW; RELAXED polling; one acquire fence at the end.
// ---------------------------------------------------------------------------
__device__ __forceinline__ void sub_bar(u32* ctr, u32 expect) {
    __syncthreads();
    if (threadIdx.x == 0) {
        __hip_atomic_fetch_add(ctr, 1u, __ATOMIC_ACQ_REL, __HIP_MEMORY_SCOPE_AGENT);
        u32 polls = 0;
        while (__hip_atomic_load(ctr, __ATOMIC_RELAXED, __HIP_MEMORY_SCOPE_AGENT) < expect) {
            __builtin_amdgcn_s_sleep(8);
            if (++polls > BAIL_) break;
        }
        __builtin_amdgcn_fence(__ATOMIC_ACQUIRE, "agent");
    }
    __syncthreads();
}

__device__ __forceinline__ void tree_bar(char* barbase, int inst, int bid) {
    __syncthreads();
    if (threadIdx.x == 0) {
        u32* leaf = (u32*)(barbase + (size_t)inst * 4096 + (size_t)(bid >> 4) * 64);
        u32* root = (u32*)(barbase + 81920 + (size_t)inst * 64);
        u32 old = __hip_atomic_fetch_add(leaf, 1u, __ATOMIC_ACQ_REL, __HIP_MEMORY_SCOPE_AGENT);
        if (old == 15u)
            __hip_atomic_fetch_add(root, 1u, __ATOMIC_ACQ_REL, __HIP_MEMORY_SCOPE_AGENT);
        u32 polls = 0;
        while (__hip_atomic_load(root, __ATOMIC_RELAXED, __HIP_MEMORY_SCOPE_AGENT) < 64u) {
            __builtin_amdgcn_s_sleep(16);
            if (++polls > BAIL_) break;
        }
        __builtin_amdgcn_fence(__ATOMIC_ACQUIRE, "agent");
    }
    __syncthreads();
}

// ---------------------------------------------------------------------------
// The whole problem in one persistent kernel. 1024 blocks x 256 threads.
// Per step: [blocks 0..63: resolve (chunk-partitioned) + transformer with
// sub-barriers] -> tree_bar -> [all blocks: fp8 argmax scan] -> tree_bar.
// Epilogue: final resolve + batched exact logits (all blocks).
// ---------------------------------------------------------------------------
__global__ __launch_bounds__(256, 4) void mega_kernel(
    const float* __restrict__ ht, const float* __restrict__ item_emb,
    const float* __restrict__ pos_emb,
    const float* __restrict__ ipw, const float* __restrict__ ipb,
    const float* __restrict__ ow, const float* __restrict__ ob,
    const float* __restrict__ l1w, const float* __restrict__ l1b,
    const float* __restrict__ l2w, const float* __restrict__ l2b,
    const float* __restrict__ f1w, const float* __restrict__ f1b,
    const float* __restrict__ f2w, const float* __restrict__ f2b,
    char* __restrict__ bar,               // barrier region (zeroed)
    u64* __restrict__ cand, u32* __restrict__ emb8,
    float* __restrict__ y_last, int* __restrict__ gen_idx,
    float* __restrict__ y0, float* __restrict__ hbuf, float* __restrict__ hbuf2,
    float* __restrict__ xl_all,
    float* __restrict__ out, float* __restrict__ gen_out)
{
    const int tid = threadIdx.x, bid = blockIdx.x;
    const int lane = tid & 63, wv = tid >> 6;

    __shared__ __align__(16) float x[640], qkv[1920], o_[640], y2[640], xps[640];
    __shared__ __align__(16) float xpl[64];
    __shared__ float att[400], rm[10], rr[10], sw[4][10], xl[64], ol[64], y2l[64], xls[64];
    __shared__ int list[256], qg[128], cnt, qcnt;
    __shared__ u64 wm[4], sbest;

    const float* ipw1 = ipw + 192 * 64;  const float* ipb1 = ipb + 192;
    const float* ow1  = ow + 64 * 64;    const float* ob1  = ob + 64;
    const float* l1w1 = l1w + 64;        const float* l1b1 = l1b + 64;
    const float* l2w1 = l2w + 64;        const float* l2b1 = l2b + 64;
    const float* f1w1 = f1w + 2048 * 64; const float* f1b1 = f1b + 2048;
    const float* f2w1 = f2w + (size_t)64 * 2048; const float* f2b1 = f2b + 64;
    u64* g_best = (u64*)(bar + 90112);   // 11 slots

    for (int t = 0; t < STEPS_; ++t) {
        const int S = t + 1;

        if (bid < NSTEP_BLK) {
            // ---------------- resolve previous argmax (t>0) ----------------
            int newidx = -1;
            if (t > 0) {
                if (tid < 64) {
                    float v = y_last[tid];
                    float m = v;
                    #pragma unroll
                    for (int o = 1; o < 64; o <<= 1) m += __shfl_xor(m, o);
                    m *= (1.f / 64.f);
                    float df = v - m;
                    float var = df * df;
                    #pragma unroll
                    for (int o = 1; o < 64; o <<= 1) var += __shfl_xor(var, o);
                    var *= (1.f / 64.f);
                    xl[tid] = df * (1.f / sqrtf(var + EPS_)) * l2w1[tid] + l2b1[tid];
                }
                if (tid == 0) { cnt = 0; qcnt = 0; sbest = 0ull; }
                __syncthreads();

                // global approx max over all chunk bests
                u64 m = 0ull;
                for (int i = tid; i < NCH; i += 256) { u64 c = cand[i]; if (c > m) m = c; }
                #pragma unroll
                for (int o = 1; o < 64; o <<= 1) { u64 xv = shfl_xor_u64(m, o); if (xv > m) m = xv; }
                if (lane == 0) wm[wv] = m;
                __syncthreads();
                if (tid == 0) {
                    u64 b = wm[0];
                    for (int i = 1; i < 4; i++) if (wm[i] > b) b = wm[i];
                    wm[0] = b;
                }
                __syncthreads();
                const float thr = unpack_val(wm[0]) - MARGIN_;

                // qualifying chunks OWNED by this block (deterministic split)
                for (int i = tid; i < NCH; i += 256) {
                    if ((i & 63) == bid && unpack_val(cand[i]) >= thr) {
                        int p = atomicAdd(&qcnt, 1);
                        if (p < 128) qg[p] = i;
                    }
                }
                __syncthreads();
                int nq = qcnt; if (nq > 128) nq = 128;

                // fp8 rescan of own chunks
                {
                    const int l4 = tid & 3, rl = tid >> 2;
                    float q[16];
                    #pragma unroll
                    for (int i = 0; i < 16; i++) q[i] = xl[l4 * 16 + i] * FP8_INV;
                    for (int ci = 0; ci < nq; ci++) {
                        const int r0 = qg[ci] * CH;
                        #pragma unroll
                        for (int half = 0; half < 2; half++) {
                            int loc = half * 64 + rl;
                            int row = r0 + loc;
                            if (loc < CH && row < V_) {
                                uint4 u = ((const uint4*)emb8)[(size_t)row * 4 + l4];
                                float p;
                                FP8_DOT16(u, q, p);
                                p += __shfl_xor(p, 1);
                                p += __shfl_xor(p, 2);
                                if (l4 == 0 && p >= thr - 1e-3f) {
                                    int pp = atomicAdd(&cnt, 1);
                                    if (pp < 256) list[pp] = row;
                                }
                            }
                        }
                    }
                }
                __syncthreads();
                int n = cnt; if (n > 256) n = 256;

                // exact fp32 rescore of own candidates
                for (int c = wv; c < n; c += 4) {
                    int row = list[c];
                    float p = xl[lane] * item_emb[(size_t)row * 64 + lane];
                    #pragma unroll
                    for (int o = 1; o < 64; o <<= 1) p += __shfl_xor(p, o);
                    if (lane == 0) atomicMax(&sbest, pack_best(p, row));
                }
                __syncthreads();
                if (tid == 0 && sbest) atomicMax(&g_best[t], sbest);
                sub_bar((u32*)(bar + 83968 + (size_t)(t * 4 + 0) * 64), NSTEP_BLK);
                u64 gb = __hip_atomic_load(&g_best[t], __ATOMIC_RELAXED, __HIP_MEMORY_SCOPE_AGENT);
                newidx = unpack_idx(gb);
                if (bid == 0 && tid == 0) {
                    gen_idx[t - 1] = newidx;
                    gen_out[t - 1] = (float)newidx;
                }
            }
            __syncthreads();

            // ---------------- transformer (layer 0 + layer 1) ----------------
            for (int i = tid; i < S * 64; i += 256) {
                int s = i >> 6, d = i & 63;
                float base;
                if (s == 0) base = ht[d];
                else base = item_emb[(size_t)((s == t) ? newidx : gen_idx[s - 1]) * 64 + d];
                x[i] = base + pos_emb[i];
            }
            __syncthreads();

            for (int i = tid; i < S * 192; i += 256) {
                int s = i / 192, j2 = i % 192;
                float acc = ipb[j2];
                const float4* wr = (const float4*)(ipw + j2 * 64);
                const float4* xr = (const float4*)(x + s * 64);
                #pragma unroll
                for (int k = 0; k < 16; k++) {
                    float4 w4 = wr[k], xv = xr[k];
                    acc += w4.x * xv.x + w4.y * xv.y + w4.z * xv.z + w4.w * xv.w;
                }
                qkv[i] = acc;
            }
            __syncthreads();

            for (int i = tid; i < 4 * S * S; i += 256) {
                int h = i / (S * S), r = i % (S * S);
                int si = r / S, ti = r % S;
                const float* qr = qkv + si * 192 + h * 16;
                const float* kr = qkv + ti * 192 + 64 + h * 16;
                float acc = 0.f;
                #pragma unroll
                for (int k = 0; k < 16; k++) acc += qr[k] * kr[k];
                att[(h * S + si) * S + ti] = acc * 0.25f;
            }
            __syncthreads();
            if (tid < 4 * S) {
                float* row = att + tid * S;
                float mx = row[0];
                for (int j2 = 1; j2 < S; j2++) mx = fmaxf(mx, row[j2]);
                float sm = 0.f;
                for (int j2 = 0; j2 < S; j2++) { float e = expf(row[j2] - mx); row[j2] = e; sm += e; }
                float inv = 1.f / sm;
                for (int j2 = 0; j2 < S; j2++) row[j2] *= inv;
            }
            __syncthreads();
            for (int i = tid; i < S * 64; i += 256) {
                int si = i >> 6, d = i & 63, h = d >> 4, dh = d & 15;
                const float* ar = att + (h * S + si) * S;
                float acc = 0.f;
                for (int ti = 0; ti < S; ti++) acc += ar[ti] * qkv[ti * 192 + 128 + h * 16 + dh];
                o_[i] = acc;
            }
            __syncthreads();
            for (int i = tid; i < S * 64; i += 256) {
                int s = i >> 6, d = i & 63;
                float acc = ob[d] + x[i];
                const float4* wr = (const float4*)(ow + d * 64);
                const float4* orow = (const float4*)(o_ + s * 64);
                #pragma unroll
                for (int k = 0; k < 16; k++) {
                    float4 w4 = wr[k], ov = orow[k];
                    acc += w4.x * ov.x + w4.y * ov.y + w4.z * ov.z + w4.w * ov.w;
                }
                y2[i] = acc;
            }
            __syncthreads();
            if (tid < S) {
                const float* yr = y2 + tid * 64;
                float m = 0.f;
                for (int k = 0; k < 64; k++) m += yr[k];
                m *= (1.f / 64.f);
                float v = 0.f;
                for (int k = 0; k < 64; k++) { float df = yr[k] - m; v += df * df; }
                rm[tid] = m;
                rr[tid] = 1.f / sqrtf(v * (1.f / 64.f) + EPS_);
            }
            __syncthreads();
            for (int i = tid; i < S * 64; i += 256) {
                int s = i >> 6, d = i & 63;
                xps[i] = (y2[i] - rm[s]) * rr[s] * l1w[d] + l1b[d];
            }
            __syncthreads();

            // FFN1 L0: this block's 32 hidden units, all S rows -> hbuf
            const int jl = tid >> 3, kp = tid & 7;
            const int j = bid * 32 + jl;
            {
                const float4* wr = (const float4*)(f1w + (size_t)j * 64);
                float4 wa = wr[kp * 2], wb = wr[kp * 2 + 1];
                float b1 = f1b[j];
                for (int s = 0; s < S; s++) {
                    const float4* xr = (const float4*)(xps + s * 64);
                    float4 xa = xr[kp * 2], xb = xr[kp * 2 + 1];
                    float p = wa.x * xa.x + wa.y * xa.y + wa.z * xa.z + wa.w * xa.w
                            + wb.x * xb.x + wb.y * xb.y + wb.z * xb.z + wb.w * xb.w;
                    p += __shfl_xor(p, 1);
                    p += __shfl_xor(p, 2);
                    p += __shfl_xor(p, 4);
                    if (kp == 0) hbuf[s * 2048 + j] = fmaxf(p + b1, 0.f);
                }
            }
            sub_bar((u32*)(bar + 83968 + (size_t)(t * 4 + 1) * 64), NSTEP_BLK);

            // FFN2 L0: one output dim per block
            {
                const int d = bid;
                const float4* w4 = (const float4*)(f2w + (size_t)d * 2048 + tid * 8);
                float4 w0 = w4[0], w1 = w4[1];
                for (int s = 0; s < S; s++) {
                    const float4* h4 = (const float4*)(hbuf + s * 2048 + tid * 8);
                    float4 h0 = h4[0], h1 = h4[1];
                    float p = w0.x * h0.x + w0.y * h0.y + w0.z * h0.z + w0.w * h0.w
                            + w1.x * h1.x + w1.y * h1.y + w1.z * h1.z + w1.w * h1.w;
                    #pragma unroll
                    for (int o = 1; o < 64; o <<= 1) p += __shfl_xor(p, o);
                    if (lane == 0) sw[wv][s] = p;
                }
                __syncthreads();
                if (tid < S)
                    y0[tid * 64 + d] = sw[0][tid] + sw[1][tid] + sw[2][tid] + sw[3][tid]
                                     + f2b[d] + xps[tid * 64 + d];
            }
            sub_bar((u32*)(bar + 83968 + (size_t)(t * 4 + 2) * 64), NSTEP_BLK);

            // LN2(y0) -> x (layer-1 input)
            for (int i = tid; i < S * 64; i += 256) y2[i] = y0[i];
            __syncthreads();
            if (tid < S) {
                const float* yr = y2 + tid * 64;
                float m = 0.f;
                for (int k = 0; k < 64; k++) m += yr[k];
                m *= (1.f / 64.f);
                float v = 0.f;
                for (int k = 0; k < 64; k++) { float df = yr[k] - m; v += df * df; }
                rm[tid] = m;
                rr[tid] = 1.f / sqrtf(v * (1.f / 64.f) + EPS_);
            }
            __syncthreads();
            for (int i = tid; i < S * 64; i += 256) {
                int s = i >> 6, d = i & 63;
                x[i] = (y2[i] - rm[s]) * rr[s] * l2w[d] + l2b[d];
            }
            __syncthreads();

            // QKV layer 1
            for (int i = tid; i < S * 192; i += 256) {
                int s = i / 192, j2 = i % 192;
                float acc = ipb1[j2];
                const float4* wr = (const float4*)(ipw1 + j2 * 64);
                const float4* xr = (const float4*)(x + s * 64);
                #pragma unroll
                for (int k = 0; k < 16; k++) {
                    float4 w4 = wr[k], xv = xr[k];
                    acc += w4.x * xv.x + w4.y * xv.y + w4.z * xv.z + w4.w * xv.w;
                }
                qkv[i] = acc;
            }
            __syncthreads();

            if (tid < 4 * S) {
                int h = tid / S, ti = tid % S;
                const float* qr = qkv + (S - 1) * 192 + h * 16;
                const float* kr = qkv + ti * 192 + 64 + h * 16;
                float acc = 0.f;
                #pragma unroll
                for (int k = 0; k < 16; k++) acc += qr[k] * kr[k];
                att[h * S + ti] = acc * 0.25f;
            }
            __syncthreads();
            if (tid < 4) {
                float* row = att + tid * S;
                float mx = row[0];
                for (int j2 = 1; j2 < S; j2++) mx = fmaxf(mx, row[j2]);
                float sm = 0.f;
                for (int j2 = 0; j2 < S; j2++) { float e = expf(row[j2] - mx); row[j2] = e; sm += e; }
                float inv = 1.f / sm;
                for (int j2 = 0; j2 < S; j2++) row[j2] *= inv;
            }
            __syncthreads();
            if (tid < 64) {
                int h = tid >> 4, dh = tid & 15;
                const float* ar = att + h * S;
                float acc = 0.f;
                for (int ti = 0; ti < S; ti++) acc += ar[ti] * qkv[ti * 192 + 128 + h * 16 + dh];
                ol[tid] = acc;
            }
            __syncthreads();
            if (tid < 64) {
                float acc = ob1[tid] + x[(S - 1) * 64 + tid];
                const float* wr = ow1 + tid * 64;
                for (int k = 0; k < 64; k++) acc += ol[k] * wr[k];
                y2l[tid] = acc;
            }
            __syncthreads();
            if (tid < 64) {
                float v = y2l[tid];
                float m = v;
                #pragma unroll
                for (int o = 1; o < 64; o <<= 1) m += __shfl_xor(m, o);
                m *= (1.f / 64.f);
                float df = v - m;
                float var = df * df;
                #pragma unroll
                for (int o = 1; o < 64; o <<= 1) var += __shfl_xor(var, o);
                float r = 1.f / sqrtf(var * (1.f / 64.f) + EPS_);
                xpl[tid] = df * r * l1w1[tid] + l1b1[tid];
            }
            __syncthreads();

            // FFN1 L1 (last row only) -> hbuf2
            {
                const float4* wr = (const float4*)(f1w1 + (size_t)j * 64);
                float4 wa = wr[kp * 2], wb = wr[kp * 2 + 1];
                const float4* xr = (const float4*)xpl;
                float4 xa = xr[kp * 2], xb = xr[kp * 2 + 1];
                float p = wa.x * xa.x + wa.y * xa.y + wa.z * xa.z + wa.w * xa.w
                        + wb.x * xb.x + wb.y * xb.y + wb.z * xb.z + wb.w * xb.w;
                p += __shfl_xor(p, 1);
                p += __shfl_xor(p, 2);
                p += __shfl_xor(p, 4);
                if (kp == 0) hbuf2[j] = fmaxf(p + f1b1[j], 0.f);
            }
            sub_bar((u32*)(bar + 83968 + (size_t)(t * 4 + 3) * 64), NSTEP_BLK);

            // FFN2 L1 (last row) -> y_last
            {
                const int d = bid;
                const float4* w4 = (const float4*)(f2w1 + (size_t)d * 2048 + tid * 8);
                const float4* h4 = (const float4*)(hbuf2 + tid * 8);
                float4 w0 = w4[0], w1 = w4[1], h0 = h4[0], h1 = h4[1];
                float p = w0.x * h0.x + w0.y * h0.y + w0.z * h0.z + w0.w * h0.w
                        + w1.x * h1.x + w1.y * h1.y + w1.z * h1.z + w1.w * h1.w;
                #pragma unroll
                for (int o = 1; o < 64; o <<= 1) p += __shfl_xor(p, o);
                if (lane == 0) sw[wv][0] = p;
                __syncthreads();
                if (tid == 0)
                    y_last[d] = sw[0][0] + sw[1][0] + sw[2][0] + sw[3][0] + f2b1[d] + xpl[d];
            }
        }

        tree_bar(bar, 2 * t, bid);   // y_last(t) visible to everyone

        // ---------------- scan phase (all 1024 blocks) ----------------
        if (tid < 64) {
            float v = y_last[tid];
            float m = v;
            #pragma unroll
            for (int o = 1; o < 64; o <<= 1) m += __shfl_xor(m, o);
            m *= (1.f / 64.f);
            float df = v - m;
            float var = df * df;
            #pragma unroll
            for (int o = 1; o < 64; o <<= 1) var += __shfl_xor(var, o);
            float r = 1.f / sqrtf(var * (1.f / 64.f) + EPS_);
            float v_ = df * r * l2w1[tid] + l2b1[tid];
            xls[tid] = (t == 0) ? v_ : v_ * FP8_INV;
            if (bid == 0) xl_all[t * 64 + tid] = v_;
        }
        __syncthreads();

        const int wgid = bid * 4 + wv;
        if (t == 0) {
            // fp32 scan + fused fp8 quantization
            const int l16 = lane & 15, rl = lane >> 4;
            float4 q = ((const float4*)xls)[l16];
            for (int g = wgid; g < NCH; g += GRID_ * 4) {
                const int r0 = g * CH;
                u64 lb = 0ull;
                for (int it = 0; it < 31; it++) {
                    int loc = it * 4 + rl;
                    int row = r0 + loc;
                    if (loc < CH && row < V_) {
                        float4 e = ((const float4*)(item_emb + (size_t)row * 64))[l16];
                        u32 pk8 = (u32)__builtin_amdgcn_cvt_pk_fp8_f32(e.x * FP8_SCALE, e.y * FP8_SCALE, 0, false);
                        pk8 = (u32)__builtin_amdgcn_cvt_pk_fp8_f32(e.z * FP8_SCALE, e.w * FP8_SCALE, (int)pk8, true);
                        emb8[(size_t)row * 16 + l16] = pk8;
                        float p = q.x * e.x + q.y * e.y + q.z * e.z + q.w * e.w;
                        p += __shfl_xor(p, 1);
                        p += __shfl_xor(p, 2);
                        p += __shfl_xor(p, 4);
                        p += __shfl_xor(p, 8);
                        if (l16 == 0) { u64 pk = pack_best(p, row); if (pk > lb) lb = pk; }
                    }
                }
                #pragma unroll
                for (int o = 1; o < 64; o <<= 1) { u64 xv = shfl_xor_u64(lb, o); if (xv > lb) lb = xv; }
                if (lane == 0) cand[g] = lb;
            }
        } else {
            // fp8 scan
            const int l4 = lane & 3, rl = lane >> 2;
            float q[16];
            #pragma unroll
            for (int i = 0; i < 16; i++) q[i] = xls[l4 * 16 + i];
            for (int g = wgid; g < NCH; g += GRID_ * 4) {
                const int r0 = g * CH;
                u64 lb = 0ull;
                for (int it = 0; it < 8; it++) {
                    int loc = it * 16 + rl;
                    int row = r0 + loc;
                    if (loc < CH && row < V_) {
                        uint4 u = ((const uint4*)emb8)[(size_t)row * 4 + l4];
                        float p;
                        FP8_DOT16(u, q, p);
                        p += __shfl_xor(p, 1);
                        p += __shfl_xor(p, 2);
                        if (l4 == 0) { u64 pk = pack_best(p, row); if (pk > lb) lb = pk; }
                    }
                }
                #pragma unroll
                for (int o = 1; o < 64; o <<= 1) { u64 xv = shfl_xor_u64(lb, o); if (xv > lb) lb = xv; }
                if (lane == 0) cand[g] = lb;
            }
        }

        tree_bar(bar, 2 * t + 1, bid);  // cand(t) visible to everyone
    }

    // ---------------- final resolve (step 9's token) ----------------
    if (bid < NSTEP_BLK) {
        if (tid < 64) {
            float v = y_last[tid];
            float m = v;
            #pragma unroll
            for (int o = 1; o < 64; o <<= 1) m += __shfl_xor(m, o);
            m *= (1.f / 64.f);
            float df = v - m;
            float var = df * df;
            #pragma unroll
            for (int o = 1; o < 64; o <<= 1) var += __shfl_xor(var, o);
            var *= (1.f / 64.f);
            xl[tid] = df * (1.f / sqrtf(var + EPS_)) * l2w1[tid] + l2b1[tid];
        }
        if (tid == 0) { cnt = 0; qcnt = 0; sbest = 0ull; }
        __syncthreads();

        u64 m = 0ull;
        for (int i = tid; i < NCH; i += 256) { u64 c = cand[i]; if (c > m) m = c; }
        #pragma unroll
        for (int o = 1; o < 64; o <<= 1) { u64 xv = shfl_xor_u64(m, o); if (xv > m) m = xv; }
        if (lane == 0) wm[wv] = m;
        __syncthreads();
        if (tid == 0) {
            u64 b = wm[0];
            for (int i = 1; i < 4; i++) if (wm[i] > b) b = wm[i];
            wm[0] = b;
        }
        __syncthreads();
        const float thr = unpack_val(wm[0]) - MARGIN_;

        for (int i = tid; i < NCH; i += 256) {
            if ((i & 63) == bid && unpack_val(cand[i]) >= thr) {
                int p = atomicAdd(&qcnt, 1);
                if (p < 128) qg[p] = i;
            }
        }
        __syncthreads();
        int nq = qcnt; if (nq > 128) nq = 128;
        {
            const int l4 = tid & 3, rl = tid >> 2;
            float q[16];
            #pragma unroll
            for (int i = 0; i < 16; i++) q[i] = xl[l4 * 16 + i] * FP8_INV;
            for (int ci = 0; ci < nq; ci++) {
                const int r0 = qg[ci] * CH;
                #pragma unroll
                for (int half = 0; half < 2; half++) {
                    int loc = half * 64 + rl;
                    int row = r0 + loc;
                    if (loc < CH && row < V_) {
                        uint4 u = ((const uint4*)emb8)[(size_t)row * 4 + l4];
                        float p;
                        FP8_DOT16(u, q, p);
                        p += __shfl_xor(p, 1);
                        p += __shfl_xor(p, 2);
                        if (l4 == 0 && p >= thr - 1e-3f) {
                            int pp = atomicAdd(&cnt, 1);
                            if (pp < 256) list[pp] = row;
                        }
                    }
                }
            }
        }
        __syncthreads();
        int n = cnt; if (n > 256) n = 256;
        for (int c = wv; c < n; c += 4) {
            int row = list[c];
            float p = xl[lane] * item_emb[(size_t)row * 64 + lane];
            #pragma unroll
            for (int o = 1; o < 64; o <<= 1) p += __shfl_xor(p, o);
            if (lane == 0) atomicMax(&sbest, pack_best(p, row));
        }
        __syncthreads();
        if (tid == 0 && sbest) atomicMax(&g_best[10], sbest);
        sub_bar((u32*)(bar + 83968 + (size_t)40 * 64), NSTEP_BLK);
        if (bid == 0 && tid == 0) {
            u64 gb = __hip_atomic_load(&g_best[10], __ATOMIC_RELAXED, __HIP_MEMORY_SCOPE_AGENT);
            gen_out[STEPS_ - 1] = (float)unpack_idx(gb);
        }
    }

    // ---------------- batched exact logits (all blocks) ----------------
    for (int i = tid; i < 640; i += 256) x[i] = xl_all[i];
    __syncthreads();
    {
        const int l4 = lane & 3, qd = lane >> 2;
        const int row_in_blk = wv * 16 + qd;        // 0..63
        for (int tile = bid; tile < V_ / 64; tile += GRID_) {
            const int row = tile * 64 + row_in_blk;
            const float4* er = (const float4*)(item_emb + (size_t)row * 64 + l4 * 16);
            float4 e0 = er[0], e1 = er[1], e2 = er[2], e3 = er[3];
            #pragma unroll
            for (int p = 0; p < 10; p++) {
                const float4* qr = (const float4*)(x + p * 64 + l4 * 16);
                float4 q0 = qr[0], q1 = qr[1], q2 = qr[2], q3 = qr[3];
                float s = q0.x*e0.x + q0.y*e0.y + q0.z*e0.z + q0.w*e0.w
                        + q1.x*e1.x + q1.y*e1.y + q1.z*e1.z + q1.w*e1.w
                        + q2.x*e2.x + q2.y*e2.y + q2.z*e2.z + q2.w*e2.w
                        + q3.x*e3.x + q3.y*e3.y + q3.z*e3.z + q3.w*e3.w;
                s += __shfl_xor(s, 1);
                s += __shfl_xor(s, 2);
                if (l4 == 0) out[(size_t)p * V_ + row] = s;
            }
        }
    }
}

extern "C" void kernel_launch(void* const* d_in, const int* in_sizes, int n_in,
                              void* d_out, int out_size, void* d_ws, size_t ws_size,
                              hipStream_t stream) {
    const float* ht       = (const float*)d_in[0];
    const float* item_emb = (const float*)d_in[1];
    const float* pos_emb  = (const float*)d_in[2];
    const float* ipw      = (const float*)d_in[3];
    const float* ipb      = (const float*)d_in[4];
    const float* ow       = (const float*)d_in[5];
    const float* ob       = (const float*)d_in[6];
    const float* l1w      = (const float*)d_in[7];
    const float* l1b      = (const float*)d_in[8];
    const float* l2w      = (const float*)d_in[9];
    const float* l2b      = (const float*)d_in[10];
    const float* f1w      = (const float*)d_in[11];
    const float* f1b      = (const float*)d_in[12];
    const float* f2w      = (const float*)d_in[13];
    const float* f2b      = (const float*)d_in[14];

    float* out = (float*)d_out;
    char* ws = (char*)d_ws;
    // layout:
    int*   gen_idx = (int*)ws;                 // [0,64)
    float* y_last  = (float*)(ws + 64);        // [64,320)
    float* y0      = (float*)(ws + 1024);      // [1024,3584)   10x64
    float* hbuf2   = (float*)(ws + 4096);      // [4096,12288)  2048
    float* xl_all  = (float*)(ws + 12288);     // [12288,14848) 10x64
    char*  bar     = ws + 16384;               // [16K,128K) barriers+g_best (zeroed)
    u64*   cand    = (u64*)(ws + 131072);      // [128K,192K) 8192 x u64
    float* hbuf    = (float*)(ws + 196608);    // [192K,272K) 10x2048
    u32*   emb8    = (u32*)(ws + 524288);      // [512K, 512K+64MB) fp8 copy
    float* gen_out = out + (size_t)STEPS_ * V_;

    hipMemsetAsync(bar, 0, 114688, stream);    // leaves+roots+subs+g_best

    mega_kernel<<<GRID_, 256, 0, stream>>>(
        ht, item_emb, pos_emb, ipw, ipb, ow, ob, l1w, l1b, l2w, l2b,
        f1w, f1b, f2w, f2b, bar, cand, emb8, y_last, gen_idx,
        y0, hbuf, hbuf2, xl_all, out, gen_out);
}